// Round 10
// baseline (1627.123 us; speedup 1.0000x reference)
//
#include <hip/hip_runtime.h>
#include <hip/hip_bf16.h>
#include <cstdint>
#include <cstddef>

#define N_NODES 262143
#define LEAF0   131071
#define N_LEAF  131072
#define HSZ     256
#define XSZ     300
#define KX      320        // XSZ padded to multiple of 32
#define KU      512
#define GATES   1024       // 4*H
#define WCOLS   512        // 2*H
#define BM      128
#define BK      32
#define TAILD   12         // persistent tail handles d = TAILD..0
#define TAILB   512        // tail grid blocks (co-resident: 2 blocks/CU)

typedef short bf16x8 __attribute__((ext_vector_type(8)));
typedef float f32x4 __attribute__((ext_vector_type(4)));
typedef _Float16 f16;

__device__ __forceinline__ unsigned short f2bf(float f) {
  union { float f; unsigned u; } v; v.f = f;
  unsigned r = v.u + 0x7FFFu + ((v.u >> 16) & 1u);   // RNE
  return (unsigned short)(r >> 16);
}
__device__ __forceinline__ unsigned cvt_pk(float lo, float hi) {
  unsigned r;
  asm("v_cvt_pk_bf16_f32 %0, %1, %2" : "=v"(r) : "v"(lo), "v"(hi));
  return r;
}
__device__ __forceinline__ bf16x8 pack8(f32x4 a0, f32x4 a1) {
  union { unsigned u[4]; bf16x8 v; } r;
  r.u[0] = cvt_pk(a0[0], a0[1]);
  r.u[1] = cvt_pk(a0[2], a0[3]);
  r.u[2] = cvt_pk(a1[0], a1[1]);
  r.u[3] = cvt_pk(a1[2], a1[3]);
  return r.v;
}
__device__ __forceinline__ void gld_lds16(const void* g, void* l) {
  __builtin_amdgcn_global_load_lds(
      (const __attribute__((address_space(1))) unsigned*)g,
      (__attribute__((address_space(3))) unsigned*)l, 16, 0, 0);
}
__device__ __forceinline__ float frcp(float x) { return __builtin_amdgcn_rcpf(x); }
__device__ __forceinline__ float fsig(float x) { return frcp(1.f + __expf(-x)); }
__device__ __forceinline__ float ftanh_(float x) { return 1.f - 2.f * frcp(1.f + __expf(2.f * x)); }

// ---------------------------------------------------------------------------
// Prep: cast + column-permute + transpose W and U into ws (bf16); also zero
// the tail-barrier counters (re-zeroed every call -> graph-replay safe).
// ---------------------------------------------------------------------------
__global__ void k_prep(const float* __restrict__ W, const float* __restrict__ U,
                       unsigned short* __restrict__ Wt, unsigned short* __restrict__ Ut,
                       unsigned* __restrict__ cnt) {
  int tid = blockIdx.x * blockDim.x + threadIdx.x;
  if (cnt && blockIdx.x == 0 && threadIdx.x < 16) cnt[threadIdx.x] = 0;
  const int totalU = GATES * KU;
  if (tid < totalU) {
    int p = tid >> 9;
    int k = tid & 511;
    int g = (p >> 4) & 3, b = p >> 6, j = p & 15;
    int oc = g * 256 + b * 16 + j;
    Ut[tid] = f2bf(U[(size_t)k * GATES + oc]);
  } else {
    int t2 = tid - totalU;
    if (t2 < WCOLS * KX) {
      int p = t2 / KX;
      int k = t2 - p * KX;
      int s = (p >> 4) & 1, b = p >> 5, j = p & 15;
      int oc = s * 256 + b * 16 + j;
      Wt[t2] = (k < XSZ) ? f2bf(W[(size_t)k * WCOLS + oc]) : (unsigned short)0;
    }
  }
}

// ---------------------------------------------------------------------------
// Leaf init (R6-proven): f32 A staging with in-loop cvt, 2-phase dbuf.
// ---------------------------------------------------------------------------
__global__ __launch_bounds__(256) void k_init(
    const float* __restrict__ x, const unsigned short* __restrict__ Wt,
    const float* __restrict__ bW, float* __restrict__ hout,
    unsigned short* __restrict__ hb, f16* __restrict__ cb)
{
  __shared__ __attribute__((aligned(16))) float          As[2][BM * BK];   // 2x16 KB
  __shared__ __attribute__((aligned(16))) unsigned short Bs[2][BM * BK];   // 2x 8 KB
  const int t = threadIdx.x;
  const int lane = t & 63, w = t >> 6;
  const int wm = w >> 1, wn = w & 1;
  const int lr = lane & 15, ls = lane >> 4;

  const int nwg = gridDim.x;
  const int wg = (blockIdx.x & 7) * (nwg >> 3) + (blockIdx.x >> 3);
  const int mblk = wg >> 2, nblk = wg & 3;
  const int tileM = mblk * BM, tileN = nblk * 128;

  f32x4 acc[4][4];
  #pragma unroll
  for (int i = 0; i < 4; ++i)
    #pragma unroll
    for (int j = 0; j < 4; ++j)
      #pragma unroll
      for (int e = 0; e < 4; ++e) acc[i][j][e] = 0.f;

  const int arow  = lane >> 3;
  const int aglog = (lane & 7) ^ arow;
  const int brow  = lane >> 2;
  const int bswz  = ((lane & 3) ^ ((lane >> 3) & 3)) * 8;

  auto stage = [&](int k0, int buf) {
    #pragma unroll
    for (int s = 0; s < 4; ++s) {
      int e = w * 4 + s;
      int col = k0 + aglog * 4;
      if (col >= XSZ) col = 0;                 // pad lanes: finite garbage * B(0) = 0
      const float* g = x + (size_t)(LEAF0 + tileM + e * 8 + arow) * XSZ + col;
      gld_lds16(g, (char*)As[buf] + e * 1024);
    }
    #pragma unroll
    for (int s = 0; s < 2; ++s) {
      int e = w * 2 + s;
      const unsigned short* g = Wt + (size_t)(tileN + e * 16 + brow) * KX + k0 + bswz;
      gld_lds16(g, (char*)Bs[buf] + e * 1024);
    }
  };

  const int NT = KX / BK;                      // 10
  stage(0, 0);
  for (int it = 0; it < NT; ++it) {
    __syncthreads();
    if (it + 1 < NT) stage((it + 1) * BK, (it + 1) & 1);
    const int cur = it & 1;
    bf16x8 af[4], bfv[4];
    #pragma unroll
    for (int i = 0; i < 4; ++i) {
      int row = wm * 64 + i * 16 + lr;
      int gx = (2 * ls) ^ (lr & 7);
      f32x4 a0 = *(const f32x4*)((const char*)As[cur] + row * 128 + (gx << 4));
      f32x4 a1 = *(const f32x4*)((const char*)As[cur] + row * 128 + ((gx ^ 1) << 4));
      af[i] = pack8(a0, a1);
    }
    #pragma unroll
    for (int j = 0; j < 4; ++j) {
      int row = wn * 64 + j * 16 + lr;
      bfv[j] = *(const bf16x8*)((const char*)Bs[cur] + row * 64 + ((ls ^ ((lr >> 1) & 3)) << 4));
    }
    #pragma unroll
    for (int i = 0; i < 4; ++i)
      #pragma unroll
      for (int j = 0; j < 4; ++j)
        acc[i][j] = __builtin_amdgcn_mfma_f32_16x16x32_bf16(af[i], bfv[j], acc[i][j], 0, 0, 0);
  }

  const int pc = tileN + wn * 64;
  #pragma unroll
  for (int i = 0; i < 4; ++i) {
    #pragma unroll
    for (int tt = 0; tt < 2; ++tt) {
      int col = (pc >> 1) + tt * 16 + lr;
      #pragma unroll
      for (int rr = 0; rr < 4; ++rr) {
        int row = tileM + wm * 64 + i * 16 + ls * 4 + rr;
        float th = ftanh_(acc[i][2 * tt][rr]     + bW[col]);
        float tc = ftanh_(acc[i][2 * tt + 1][rr] + bW[256 + col]);
        size_t node = (size_t)LEAF0 + row;
        hout[node * HSZ + col] = th;
        hb[node * HSZ + col]   = f2bf(th);
        cb[node * HSZ + col]   = (f16)tc;
      }
    }
  }
}

// ---------------------------------------------------------------------------
// One tree level (d >= 13), fused, all-bf16 staging, 2-phase dbuf (R6-proven).
// ---------------------------------------------------------------------------
__global__ __launch_bounds__(256) void k_level(
    float* __restrict__ hbuf, unsigned short* __restrict__ hb,
    f16* __restrict__ cb,
    const unsigned short* __restrict__ Ut, const float* __restrict__ bU,
    int a, int m)
{
  __shared__ __attribute__((aligned(16))) unsigned short As[2][BM * BK];   // 2x8 KB
  __shared__ __attribute__((aligned(16))) unsigned short Bs[2][BM * BK];   // 2x8 KB
  const int t = threadIdx.x;
  const int lane = t & 63, w = t >> 6;
  const int wm = w >> 1, wn = w & 1;
  const int lr = lane & 15, ls = lane >> 4;

  const int nwg = gridDim.x;
  const int wg = (blockIdx.x & 7) * (nwg >> 3) + (blockIdx.x >> 3);
  const int mblk = wg >> 3, nblk = wg & 7;
  const int tileM = mblk * BM, tileN = nblk * 128;

  f32x4 acc[4][4];
  #pragma unroll
  for (int i = 0; i < 4; ++i)
    #pragma unroll
    for (int j = 0; j < 4; ++j)
      #pragma unroll
      for (int e = 0; e < 4; ++e) acc[i][j][e] = 0.f;

  const unsigned short* Abase = hb + (size_t)(2 * a + 1) * HSZ + (size_t)tileM * KU;
  const unsigned short* Bbase = Ut + (size_t)tileN * KU;

  const int brow = lane >> 2;
  const int bswz = ((lane & 3) ^ ((lane >> 3) & 3)) * 8;

  auto stage = [&](int k0, int buf) {
    #pragma unroll
    for (int s = 0; s < 2; ++s) {
      int e = w * 2 + s;
      const unsigned short* g = Abase + (size_t)(e * 16 + brow) * KU + k0 + bswz;
      gld_lds16(g, (char*)As[buf] + e * 1024);
    }
    #pragma unroll
    for (int s = 0; s < 2; ++s) {
      int e = w * 2 + s;
      const unsigned short* g = Bbase + (size_t)(e * 16 + brow) * KU + k0 + bswz;
      gld_lds16(g, (char*)Bs[buf] + e * 1024);
    }
  };

  const int NT = KU / BK;                      // 16
  stage(0, 0);
  for (int it = 0; it < NT; ++it) {
    __syncthreads();
    if (it + 1 < NT) stage((it + 1) * BK, (it + 1) & 1);
    const int cur = it & 1;
    bf16x8 af[4], bfv[4];
    #pragma unroll
    for (int i = 0; i < 4; ++i) {
      int row = wm * 64 + i * 16 + lr;
      af[i] = *(const bf16x8*)((const char*)As[cur] + row * 64 + ((ls ^ ((lr >> 1) & 3)) << 4));
    }
    #pragma unroll
    for (int j = 0; j < 4; ++j) {
      int row = wn * 64 + j * 16 + lr;
      bfv[j] = *(const bf16x8*)((const char*)Bs[cur] + row * 64 + ((ls ^ ((lr >> 1) & 3)) << 4));
    }
    #pragma unroll
    for (int i = 0; i < 4; ++i)
      #pragma unroll
      for (int j = 0; j < 4; ++j)
        acc[i][j] = __builtin_amdgcn_mfma_f32_16x16x32_bf16(af[i], bfv[j], acc[i][j], 0, 0, 0);
  }

  const int pc = tileN + wn * 64;            // frag j == gate g
  const int col = (pc >> 2) + lr;
  const float bi = bU[col], bo = bU[256 + col], bu = bU[512 + col], bff = bU[768 + col];
  #pragma unroll
  for (int i = 0; i < 4; ++i) {
    #pragma unroll
    for (int rr = 0; rr < 4; ++rr) {
      int noderow = tileM + wm * 64 + i * 16 + ls * 4 + rr;
      if (noderow < m) {
        float iv = fsig  (acc[i][0][rr] + bi);
        float ov = fsig  (acc[i][1][rr] + bo);
        float uv = ftanh_(acc[i][2][rr] + bu);
        float fv = fsig  (acc[i][3][rr] + bff);
        size_t node = (size_t)a + noderow;
        float cl = (float)cb[(2 * node + 1) * HSZ + col];
        float cr = (float)cb[(2 * node + 2) * HSZ + col];
        float cn = iv * uv + fv * (cl + cr);
        float hn = ov * ftanh_(cn);
        hbuf[node * HSZ + col] = hn;
        hb[node * HSZ + col]   = f2bf(hn);
        cb[node * HSZ + col]   = (f16)cn;
      }
    }
  }
}

// ---------------------------------------------------------------------------
// Per-wave tile body (16 rows x 64 perm-cols), direct global reads.
// ---------------------------------------------------------------------------
__device__ __forceinline__ void small_tile(
    float* hbuf, unsigned short* hb, f16* cb,
    const unsigned short* Ut, const float* bU,
    int a, int m, int rb, int nb, int lr, int ls)
{
  const unsigned short* Arow = hb + (size_t)(2 * a + 1) * HSZ + (size_t)(rb + lr) * KU;
  const unsigned short* B0 = Ut + (size_t)(nb + lr) * KU;

  f32x4 acc[4];
  #pragma unroll
  for (int g = 0; g < 4; ++g)
    #pragma unroll
    for (int e = 0; e < 4; ++e) acc[g][e] = 0.f;

  for (int k0 = 0; k0 < KU; k0 += BK) {
    bf16x8 av = *(const bf16x8*)(Arow + k0 + ls * 8);
    #pragma unroll
    for (int g = 0; g < 4; ++g) {
      bf16x8 bv = *(const bf16x8*)(B0 + (size_t)g * 16 * KU + k0 + ls * 8);
      acc[g] = __builtin_amdgcn_mfma_f32_16x16x32_bf16(av, bv, acc[g], 0, 0, 0);
    }
  }

  const int col = (nb >> 2) + lr;
  const float bi = bU[col], bo = bU[256 + col], bu = bU[512 + col], bff = bU[768 + col];
  #pragma unroll
  for (int rr = 0; rr < 4; ++rr) {
    int row = rb + ls * 4 + rr;
    if (row < m) {
      float iv = fsig  (acc[0][rr] + bi);
      float ov = fsig  (acc[1][rr] + bo);
      float uv = ftanh_(acc[2][rr] + bu);
      float fv = fsig  (acc[3][rr] + bff);
      size_t node = (size_t)a + row;
      float cl = (float)cb[(2 * node + 1) * HSZ + col];
      float cr = (float)cb[(2 * node + 2) * HSZ + col];
      float cn = iv * uv + fv * (cl + cr);
      float hn = ov * ftanh_(cn);
      hbuf[node * HSZ + col] = hn;
      hb[node * HSZ + col]   = f2bf(hn);
      cb[node * HSZ + col]   = (f16)cn;
    }
  }
}

// ---------------------------------------------------------------------------
// Persistent tail: levels d = TAILD..0 in one launch; device-scope barrier
// (per-level counter, zeroed by k_prep) between levels. 512 blocks x 256 thr,
// 0 LDS -> trivially co-resident (2 blocks/CU).
// ---------------------------------------------------------------------------
__global__ __launch_bounds__(256) void k_tail(
    float* __restrict__ hbuf, unsigned short* __restrict__ hb,
    f16* __restrict__ cb,
    const unsigned short* __restrict__ Ut, const float* __restrict__ bU,
    unsigned* __restrict__ cnt)
{
  const int t = threadIdx.x;
  const int lane = t & 63, w = t >> 6;
  const int lr = lane & 15, ls = lane >> 4;
  const int wid = blockIdx.x * 4 + w;          // 0 .. TAILB*4-1
  const int nwaves = TAILB * 4;

  for (int d = TAILD; d >= 0; --d) {
    const int m = 1 << d, a = m - 1;
    const int ntiles = ((m + 15) >> 4) * 16;   // row-tiles x 16 col-tiles
    for (int tile = wid; tile < ntiles; tile += nwaves) {
      int rb = (tile >> 4) * 16;
      int nb = (tile & 15) * 64;
      small_tile(hbuf, hb, cb, Ut, bU, a, m, rb, nb, lr, ls);
    }
    if (d > 0) {                               // device barrier before next level
      __syncthreads();
      if (t == 0) {
        __threadfence();
        __hip_atomic_fetch_add(&cnt[d], 1u, __ATOMIC_ACQ_REL, __HIP_MEMORY_SCOPE_AGENT);
        while (__hip_atomic_load(&cnt[d], __ATOMIC_ACQUIRE, __HIP_MEMORY_SCOPE_AGENT) < (unsigned)TAILB) {}
        __threadfence();
      }
      __syncthreads();
    }
  }
}

// ---------------------------------------------------------------------------
// Fallback small-level kernel (per-level launch) if ws lacks counter space.
// ---------------------------------------------------------------------------
__global__ __launch_bounds__(256) void k_small(
    float* __restrict__ hbuf, unsigned short* __restrict__ hb,
    f16* __restrict__ cb,
    const unsigned short* __restrict__ Ut, const float* __restrict__ bU,
    int a, int m)
{
  const int t = threadIdx.x;
  const int lane = t & 63, w = t >> 6;
  const int lr = lane & 15, ls = lane >> 4;
  const int rb = (blockIdx.x >> 4) * 64 + w * 16;
  const int nb = (blockIdx.x & 15) * 64;
  if (rb >= m) return;
  small_tile(hbuf, hb, cb, Ut, bU, a, m, rb, nb, lr, ls);
}

// ---------------------------------------------------------------------------
extern "C" void kernel_launch(void* const* d_in, const int* in_sizes, int n_in,
                              void* d_out, int out_size, void* d_ws, size_t ws_size,
                              hipStream_t stream) {
  const float* x  = (const float*)d_in[0];
  const float* W  = (const float*)d_in[1];
  const float* bW = (const float*)d_in[2];
  const float* U  = (const float*)d_in[3];
  const float* bU = (const float*)d_in[4];
  // d_in[5] = children (int32) — structurally 2i+1/2i+2 (complete binary tree).
  float* hout = (float*)d_out;
  char*  ws   = (char*)d_ws;

  // ws layout (269,810,688 B core + 64 B counters):
  unsigned short* Ut = (unsigned short*)ws;                         // 1,048,576
  unsigned short* Wt = (unsigned short*)(ws + 1048576);             //   327,680
  f16*            cb = (f16*)(ws + 1048576 + 327680);               // 134,217,216
  unsigned short* hb = (unsigned short*)(ws + 1048576 + 327680
                                         + (size_t)N_NODES * HSZ * 2); // 134,217,216
  const size_t CNTOFF = 1048576ull + 327680ull + 2ull * 134217216ull;  // 269,810,688
  unsigned* cnt = (unsigned*)(ws + CNTOFF);
  bool has_cnt = (ws_size >= CNTOFF + 64);

  const int preptot = GATES * KU + WCOLS * KX;
  hipLaunchKernelGGL(k_prep, dim3((preptot + 255) / 256), dim3(256), 0, stream,
                     W, U, Wt, Ut, has_cnt ? cnt : (unsigned*)nullptr);

  hipLaunchKernelGGL(k_init, dim3((N_LEAF / BM) * 4), dim3(256), 0, stream,
                     x, Wt, bW, hout, hb, cb);

  for (int d = 16; d > TAILD; --d) {
    int m = 1 << d, a = m - 1;
    hipLaunchKernelGGL(k_level, dim3((m / BM) * 8), dim3(256), 0, stream,
                       hout, hb, cb, Ut, bU, a, m);
  }

  if (has_cnt) {
    hipLaunchKernelGGL(k_tail, dim3(TAILB), dim3(256), 0, stream,
                       hout, hb, cb, Ut, bU, cnt);
  } else {
    for (int d = TAILD; d >= 0; --d) {
      int m = 1 << d, a = m - 1;
      if (d >= 12) {
        hipLaunchKernelGGL(k_level, dim3((m / BM) * 8), dim3(256), 0, stream,
                           hout, hb, cb, Ut, bU, a, m);
      } else {
        int gm = (m + 63) / 64; if (gm < 1) gm = 1;
        hipLaunchKernelGGL(k_small, dim3(gm * 16), dim3(256), 0, stream,
                           hout, hb, cb, Ut, bU, a, m);
      }
    }
  }
}

// Round 11
// 628.312 us; speedup vs baseline: 2.5897x; 2.5897x over previous
//
#include <hip/hip_runtime.h>
#include <hip/hip_bf16.h>
#include <cstdint>
#include <cstddef>

#define N_NODES 262143
#define LEAF0   131071
#define N_LEAF  131072
#define HSZ     256
#define XSZ     300
#define KX      320        // XSZ padded to multiple of 32
#define KU      512
#define GATES   1024       // 4*H
#define WCOLS   512        // 2*H
#define BM      128
#define BK      32

typedef short bf16x8 __attribute__((ext_vector_type(8)));
typedef float f32x4 __attribute__((ext_vector_type(4)));
typedef unsigned u32x4 __attribute__((ext_vector_type(4)));
typedef _Float16 f16;

__device__ __forceinline__ unsigned short f2bf(float f) {
  union { float f; unsigned u; } v; v.f = f;
  unsigned r = v.u + 0x7FFFu + ((v.u >> 16) & 1u);   // RNE
  return (unsigned short)(r >> 16);
}
__device__ __forceinline__ unsigned cvt_pk(float lo, float hi) {
  unsigned r;
  asm("v_cvt_pk_bf16_f32 %0, %1, %2" : "=v"(r) : "v"(lo), "v"(hi));
  return r;
}
__device__ __forceinline__ void gld_lds16(const void* g, void* l) {
  __builtin_amdgcn_global_load_lds(
      (const __attribute__((address_space(1))) unsigned*)g,
      (__attribute__((address_space(3))) unsigned*)l, 16, 0, 0);
}
__device__ __forceinline__ float frcp(float x) { return __builtin_amdgcn_rcpf(x); }
__device__ __forceinline__ float fsig(float x) { return frcp(1.f + __expf(-x)); }
__device__ __forceinline__ float ftanh_(float x) { return 1.f - 2.f * frcp(1.f + __expf(2.f * x)); }

// ---------------------------------------------------------------------------
// Prep: cast + column-permute + transpose W and U into ws (bf16).
// U perm col p = 64*b + 16*g + j  <-  orig col 256*g + 16*b + j
// W perm col p = 32*b + 16*s + j  <-  orig col 256*s + 16*b + j
// ---------------------------------------------------------------------------
__global__ void k_prep(const float* __restrict__ W, const float* __restrict__ U,
                       unsigned short* __restrict__ Wt, unsigned short* __restrict__ Ut) {
  int tid = blockIdx.x * blockDim.x + threadIdx.x;
  const int totalU = GATES * KU;
  if (tid < totalU) {
    int p = tid >> 9;
    int k = tid & 511;
    int g = (p >> 4) & 3, b = p >> 6, j = p & 15;
    int oc = g * 256 + b * 16 + j;
    Ut[tid] = f2bf(U[(size_t)k * GATES + oc]);
  } else {
    int t2 = tid - totalU;
    if (t2 < WCOLS * KX) {
      int p = t2 / KX;
      int k = t2 - p * KX;
      int s = (p >> 4) & 1, b = p >> 5, j = p & 15;
      int oc = s * 256 + b * 16 + j;
      Wt[t2] = (k < XSZ) ? f2bf(W[(size_t)k * WCOLS + oc]) : (unsigned short)0;
    }
  }
}

// ---------------------------------------------------------------------------
// Leaf init: t = tanh(x @ W + bW); h -> hout(f32)+hb(bf16), c -> cb(f16).
// A is REG-STAGED: global f32 -> cvt_pk -> swizzled ds_write bf16 (loads
// issued before compute, writes after — T14 split). K-loop reads A as bf16.
// B staged via global_load_lds (pre-swizzled source). 32 KB LDS total.
// ---------------------------------------------------------------------------
__global__ __launch_bounds__(256) void k_init(
    const float* __restrict__ x, const unsigned short* __restrict__ Wt,
    const float* __restrict__ bW, float* __restrict__ hout,
    unsigned short* __restrict__ hb, f16* __restrict__ cb)
{
  __shared__ __attribute__((aligned(16))) unsigned short As[2][BM * BK];   // 2x8 KB
  __shared__ __attribute__((aligned(16))) unsigned short Bs[2][BM * BK];   // 2x8 KB
  const int t = threadIdx.x;
  const int lane = t & 63, w = t >> 6;
  const int wm = w >> 1, wn = w & 1;
  const int lr = lane & 15, ls = lane >> 4;

  const int nwg = gridDim.x;
  const int wg = (blockIdx.x & 7) * (nwg >> 3) + (blockIdx.x >> 3);
  const int mblk = wg >> 2, nblk = wg & 3;
  const int tileM = mblk * BM, tileN = nblk * 128;

  f32x4 acc[4][4];
  #pragma unroll
  for (int i = 0; i < 4; ++i)
    #pragma unroll
    for (int j = 0; j < 4; ++j)
      #pragma unroll
      for (int e = 0; e < 4; ++e) acc[i][j][e] = 0.f;

  // A reg-stage mapping: thread -> (row ar, 16-col half ah)
  const int ar = t >> 1, ah = t & 1;
  const size_t xrow = (size_t)(LEAF0 + tileM + ar) * XSZ;
  const size_t xend = (size_t)N_NODES * XSZ - 4;     // clamp for 16B-equipped loads
  const int asw = (ar >> 1) & 3;                     // A write-granule XOR (matches read)

  // B gld_lds mapping (proven path)
  const int brow = lane >> 2;
  const int bswz = ((lane & 3) ^ ((lane >> 3) & 3)) * 8;

  auto loadA = [&](int k0, f32x4 v[4]) {
    size_t base = xrow + k0 + ah * 16;
    #pragma unroll
    for (int q = 0; q < 4; ++q) {
      size_t o = base + q * 4;
      if (o > xend) o = xend;                        // garbage cols * Wt zero-pad = 0
      v[q] = *(const f32x4*)(x + o);
    }
  };
  auto writeA = [&](int buf, const f32x4 v[4]) {
    u32x4 lo, hi;
    lo[0] = cvt_pk(v[0][0], v[0][1]); lo[1] = cvt_pk(v[0][2], v[0][3]);
    lo[2] = cvt_pk(v[1][0], v[1][1]); lo[3] = cvt_pk(v[1][2], v[1][3]);
    hi[0] = cvt_pk(v[2][0], v[2][1]); hi[1] = cvt_pk(v[2][2], v[2][3]);
    hi[2] = cvt_pk(v[3][0], v[3][1]); hi[3] = cvt_pk(v[3][2], v[3][3]);
    char* basep = (char*)As[buf] + ar * 64;
    *(u32x4*)(basep + (((ah * 2)     ^ asw) << 4)) = lo;
    *(u32x4*)(basep + (((ah * 2 + 1) ^ asw) << 4)) = hi;
  };
  auto stageB = [&](int k0, int buf) {
    #pragma unroll
    for (int s = 0; s < 2; ++s) {
      int e = w * 2 + s;
      const unsigned short* g = Wt + (size_t)(tileN + e * 16 + brow) * KX + k0 + bswz;
      gld_lds16(g, (char*)Bs[buf] + e * 1024);
    }
  };

  const int NT = KX / BK;                      // 10
  {
    f32x4 v[4];
    loadA(0, v);
    stageB(0, 0);
    writeA(0, v);
  }
  for (int it = 0; it < NT; ++it) {
    __syncthreads();                           // buf(cur) complete (gld_lds + ds_write)
    const int cur = it & 1;
    f32x4 v[4];
    if (it + 1 < NT) {                         // issue next-tile loads early
      stageB((it + 1) * BK, cur ^ 1);
      loadA((it + 1) * BK, v);
    }
    bf16x8 af[4], bfv[4];
    #pragma unroll
    for (int i = 0; i < 4; ++i) {
      int row = wm * 64 + i * 16 + lr;
      af[i] = *(const bf16x8*)((const char*)As[cur] + row * 64 + ((ls ^ ((lr >> 1) & 3)) << 4));
    }
    #pragma unroll
    for (int j = 0; j < 4; ++j) {
      int row = wn * 64 + j * 16 + lr;
      bfv[j] = *(const bf16x8*)((const char*)Bs[cur] + row * 64 + ((ls ^ ((lr >> 1) & 3)) << 4));
    }
    #pragma unroll
    for (int i = 0; i < 4; ++i)
      #pragma unroll
      for (int j = 0; j < 4; ++j)
        acc[i][j] = __builtin_amdgcn_mfma_f32_16x16x32_bf16(af[i], bfv[j], acc[i][j], 0, 0, 0);
    if (it + 1 < NT) writeA(cur ^ 1, v);       // write-late; drained by next barrier
  }

  const int pc = tileN + wn * 64;
  #pragma unroll
  for (int i = 0; i < 4; ++i) {
    #pragma unroll
    for (int tt = 0; tt < 2; ++tt) {
      int col = (pc >> 1) + tt * 16 + lr;
      #pragma unroll
      for (int rr = 0; rr < 4; ++rr) {
        int row = tileM + wm * 64 + i * 16 + ls * 4 + rr;
        float th = ftanh_(acc[i][2 * tt][rr]     + bW[col]);
        float tc = ftanh_(acc[i][2 * tt + 1][rr] + bW[256 + col]);
        size_t node = (size_t)LEAF0 + row;
        hout[node * HSZ + col] = th;
        hb[node * HSZ + col]   = f2bf(th);
        cb[node * HSZ + col]   = (f16)tc;
      }
    }
  }
}

// ---------------------------------------------------------------------------
// One tree level (d >= 12), fused, all-bf16 staging, 2-phase dbuf (R6-proven).
// ---------------------------------------------------------------------------
__global__ __launch_bounds__(256) void k_level(
    float* __restrict__ hbuf, unsigned short* __restrict__ hb,
    f16* __restrict__ cb,
    const unsigned short* __restrict__ Ut, const float* __restrict__ bU,
    int a, int m)
{
  __shared__ __attribute__((aligned(16))) unsigned short As[2][BM * BK];   // 2x8 KB
  __shared__ __attribute__((aligned(16))) unsigned short Bs[2][BM * BK];   // 2x8 KB
  const int t = threadIdx.x;
  const int lane = t & 63, w = t >> 6;
  const int wm = w >> 1, wn = w & 1;
  const int lr = lane & 15, ls = lane >> 4;

  const int nwg = gridDim.x;
  const int wg = (blockIdx.x & 7) * (nwg >> 3) + (blockIdx.x >> 3);
  const int mblk = wg >> 3, nblk = wg & 7;
  const int tileM = mblk * BM, tileN = nblk * 128;

  f32x4 acc[4][4];
  #pragma unroll
  for (int i = 0; i < 4; ++i)
    #pragma unroll
    for (int j = 0; j < 4; ++j)
      #pragma unroll
      for (int e = 0; e < 4; ++e) acc[i][j][e] = 0.f;

  const unsigned short* Abase = hb + (size_t)(2 * a + 1) * HSZ + (size_t)tileM * KU;
  const unsigned short* Bbase = Ut + (size_t)tileN * KU;

  const int brow = lane >> 2;
  const int bswz = ((lane & 3) ^ ((lane >> 3) & 3)) * 8;

  auto stage = [&](int k0, int buf) {
    #pragma unroll
    for (int s = 0; s < 2; ++s) {
      int e = w * 2 + s;
      const unsigned short* g = Abase + (size_t)(e * 16 + brow) * KU + k0 + bswz;
      gld_lds16(g, (char*)As[buf] + e * 1024);
    }
    #pragma unroll
    for (int s = 0; s < 2; ++s) {
      int e = w * 2 + s;
      const unsigned short* g = Bbase + (size_t)(e * 16 + brow) * KU + k0 + bswz;
      gld_lds16(g, (char*)Bs[buf] + e * 1024);
    }
  };

  const int NT = KU / BK;                      // 16
  stage(0, 0);
  for (int it = 0; it < NT; ++it) {
    __syncthreads();
    if (it + 1 < NT) stage((it + 1) * BK, (it + 1) & 1);
    const int cur = it & 1;
    bf16x8 af[4], bfv[4];
    #pragma unroll
    for (int i = 0; i < 4; ++i) {
      int row = wm * 64 + i * 16 + lr;
      af[i] = *(const bf16x8*)((const char*)As[cur] + row * 64 + ((ls ^ ((lr >> 1) & 3)) << 4));
    }
    #pragma unroll
    for (int j = 0; j < 4; ++j) {
      int row = wn * 64 + j * 16 + lr;
      bfv[j] = *(const bf16x8*)((const char*)Bs[cur] + row * 64 + ((ls ^ ((lr >> 1) & 3)) << 4));
    }
    #pragma unroll
    for (int i = 0; i < 4; ++i)
      #pragma unroll
      for (int j = 0; j < 4; ++j)
        acc[i][j] = __builtin_amdgcn_mfma_f32_16x16x32_bf16(af[i], bfv[j], acc[i][j], 0, 0, 0);
  }

  const int pc = tileN + wn * 64;            // frag j == gate g
  const int col = (pc >> 2) + lr;
  const float bi = bU[col], bo = bU[256 + col], bu = bU[512 + col], bff = bU[768 + col];
  #pragma unroll
  for (int i = 0; i < 4; ++i) {
    #pragma unroll
    for (int rr = 0; rr < 4; ++rr) {
      int noderow = tileM + wm * 64 + i * 16 + ls * 4 + rr;
      if (noderow < m) {
        float iv = fsig  (acc[i][0][rr] + bi);
        float ov = fsig  (acc[i][1][rr] + bo);
        float uv = ftanh_(acc[i][2][rr] + bu);
        float fv = fsig  (acc[i][3][rr] + bff);
        size_t node = (size_t)a + noderow;
        float cl = (float)cb[(2 * node + 1) * HSZ + col];
        float cr = (float)cb[(2 * node + 2) * HSZ + col];
        float cn = iv * uv + fv * (cl + cr);
        float hn = ov * ftanh_(cn);
        hbuf[node * HSZ + col] = hn;
        hb[node * HSZ + col]   = f2bf(hn);
        cb[node * HSZ + col]   = (f16)cn;
      }
    }
  }
}

// ---------------------------------------------------------------------------
// Small levels (d <= 11): one wave per 16x64 output tile, direct global reads
// (A slab and Ut are L2-resident at these sizes). grid = max(1,m/64)*16.
// ---------------------------------------------------------------------------
__global__ __launch_bounds__(256) void k_small(
    float* __restrict__ hbuf, unsigned short* __restrict__ hb,
    f16* __restrict__ cb,
    const unsigned short* __restrict__ Ut, const float* __restrict__ bU,
    int a, int m)
{
  const int t = threadIdx.x;
  const int lane = t & 63, w = t >> 6;
  const int lr = lane & 15, ls = lane >> 4;
  const int rb = (blockIdx.x >> 4) * 64 + w * 16;
  const int nb = (blockIdx.x & 15) * 64;
  if (rb >= m) return;

  const unsigned short* Arow = hb + (size_t)(2 * a + 1) * HSZ + (size_t)(rb + lr) * KU;
  const unsigned short* B0 = Ut + (size_t)(nb + lr) * KU;

  f32x4 acc[4];
  #pragma unroll
  for (int g = 0; g < 4; ++g)
    #pragma unroll
    for (int e = 0; e < 4; ++e) acc[g][e] = 0.f;

  for (int k0 = 0; k0 < KU; k0 += BK) {
    bf16x8 av = *(const bf16x8*)(Arow + k0 + ls * 8);
    #pragma unroll
    for (int g = 0; g < 4; ++g) {
      bf16x8 bv = *(const bf16x8*)(B0 + (size_t)g * 16 * KU + k0 + ls * 8);
      acc[g] = __builtin_amdgcn_mfma_f32_16x16x32_bf16(av, bv, acc[g], 0, 0, 0);
    }
  }

  const int col = (nb >> 2) + lr;
  const float bi = bU[col], bo = bU[256 + col], bu = bU[512 + col], bff = bU[768 + col];
  #pragma unroll
  for (int rr = 0; rr < 4; ++rr) {
    int row = rb + ls * 4 + rr;
    if (row < m) {
      float iv = fsig  (acc[0][rr] + bi);
      float ov = fsig  (acc[1][rr] + bo);
      float uv = ftanh_(acc[2][rr] + bu);
      float fv = fsig  (acc[3][rr] + bff);
      size_t node = (size_t)a + row;
      float cl = (float)cb[(2 * node + 1) * HSZ + col];
      float cr = (float)cb[(2 * node + 2) * HSZ + col];
      float cn = iv * uv + fv * (cl + cr);
      float hn = ov * ftanh_(cn);
      hbuf[node * HSZ + col] = hn;
      hb[node * HSZ + col]   = f2bf(hn);
      cb[node * HSZ + col]   = (f16)cn;
    }
  }
}

// ---------------------------------------------------------------------------
extern "C" void kernel_launch(void* const* d_in, const int* in_sizes, int n_in,
                              void* d_out, int out_size, void* d_ws, size_t ws_size,
                              hipStream_t stream) {
  const float* x  = (const float*)d_in[0];
  const float* W  = (const float*)d_in[1];
  const float* bW = (const float*)d_in[2];
  const float* U  = (const float*)d_in[3];
  const float* bU = (const float*)d_in[4];
  // d_in[5] = children (int32) — structurally 2i+1/2i+2 (complete binary tree).
  float* hout = (float*)d_out;
  char*  ws   = (char*)d_ws;

  // ws layout (269,810,688 B total):
  unsigned short* Ut = (unsigned short*)ws;                         // 1,048,576
  unsigned short* Wt = (unsigned short*)(ws + 1048576);             //   327,680
  f16*            cb = (f16*)(ws + 1048576 + 327680);               // 134,217,216
  unsigned short* hb = (unsigned short*)(ws + 1048576 + 327680
                                         + (size_t)N_NODES * HSZ * 2); // 134,217,216

  const int preptot = GATES * KU + WCOLS * KX;
  hipLaunchKernelGGL(k_prep, dim3((preptot + 255) / 256), dim3(256), 0, stream, W, U, Wt, Ut);

  hipLaunchKernelGGL(k_init, dim3((N_LEAF / BM) * 4), dim3(256), 0, stream,
                     x, Wt, bW, hout, hb, cb);

  for (int d = 16; d >= 0; --d) {
    int m = 1 << d, a = m - 1;
    if (d >= 12) {
      hipLaunchKernelGGL(k_level, dim3((m / BM) * 8), dim3(256), 0, stream,
                         hout, hb, cb, Ut, bU, a, m);
    } else {
      int gm = (m + 63) / 64; if (gm < 1) gm = 1;
      hipLaunchKernelGGL(k_small, dim3(gm * 16), dim3(256), 0, stream,
                         hout, hb, cb, Ut, bU, a, m);
    }
  }
}

// Round 12
// 595.071 us; speedup vs baseline: 2.7343x; 1.0559x over previous
//
#include <hip/hip_runtime.h>
#include <hip/hip_bf16.h>
#include <cstdint>
#include <cstddef>

#define N_NODES 262143
#define LEAF0   131071
#define N_LEAF  131072
#define HSZ     256
#define XSZ     300
#define KX      320        // XSZ padded to multiple of 32
#define KU      512
#define GATES   1024       // 4*H
#define WCOLS   512        // 2*H
#define BM      128
#define BK      32

typedef short bf16x8 __attribute__((ext_vector_type(8)));
typedef float f32x4 __attribute__((ext_vector_type(4)));
typedef _Float16 f16;

__device__ __forceinline__ unsigned short f2bf(float f) {
  union { float f; unsigned u; } v; v.f = f;
  unsigned r = v.u + 0x7FFFu + ((v.u >> 16) & 1u);   // RNE
  return (unsigned short)(r >> 16);
}
__device__ __forceinline__ unsigned cvt_pk(float lo, float hi) {
  unsigned r;
  asm("v_cvt_pk_bf16_f32 %0, %1, %2" : "=v"(r) : "v"(lo), "v"(hi));
  return r;
}
__device__ __forceinline__ bf16x8 pack8(f32x4 a0, f32x4 a1) {
  union { unsigned u[4]; bf16x8 v; } r;
  r.u[0] = cvt_pk(a0[0], a0[1]);
  r.u[1] = cvt_pk(a0[2], a0[3]);
  r.u[2] = cvt_pk(a1[0], a1[1]);
  r.u[3] = cvt_pk(a1[2], a1[3]);
  return r.v;
}
__device__ __forceinline__ void gld_lds16(const void* g, void* l) {
  __builtin_amdgcn_global_load_lds(
      (const __attribute__((address_space(1))) unsigned*)g,
      (__attribute__((address_space(3))) unsigned*)l, 16, 0, 0);
}
__device__ __forceinline__ float frcp(float x) { return __builtin_amdgcn_rcpf(x); }
__device__ __forceinline__ float fsig(float x) { return frcp(1.f + __expf(-x)); }
__device__ __forceinline__ float ftanh_(float x) { return 1.f - 2.f * frcp(1.f + __expf(2.f * x)); }

// ---------------------------------------------------------------------------
// Prep: cast + column-permute + transpose W and U into ws (bf16).
// U perm col p = 64*b + 16*g + j  <-  orig col 256*g + 16*b + j
// W perm col p = 32*b + 16*s + j  <-  orig col 256*s + 16*b + j
// ---------------------------------------------------------------------------
__global__ void k_prep(const float* __restrict__ W, const float* __restrict__ U,
                       unsigned short* __restrict__ Wt, unsigned short* __restrict__ Ut) {
  int tid = blockIdx.x * blockDim.x + threadIdx.x;
  const int totalU = GATES * KU;
  if (tid < totalU) {
    int p = tid >> 9;
    int k = tid & 511;
    int g = (p >> 4) & 3, b = p >> 6, j = p & 15;
    int oc = g * 256 + b * 16 + j;
    Ut[tid] = f2bf(U[(size_t)k * GATES + oc]);
  } else {
    int t2 = tid - totalU;
    if (t2 < WCOLS * KX) {
      int p = t2 / KX;
      int k = t2 - p * KX;
      int s = (p >> 4) & 1, b = p >> 5, j = p & 15;
      int oc = s * 256 + b * 16 + j;
      Wt[t2] = (k < XSZ) ? f2bf(W[(size_t)k * WCOLS + oc]) : (unsigned short)0;
    }
  }
}

// ---------------------------------------------------------------------------
// Leaf init (R6-proven): t = tanh(x @ W + bW); h -> hout(f32)+hb(bf16),
// c -> cb(f16). A = x f32 via gld_lds (8-granule XOR swizzle, in-loop cvt),
// B = Wt bf16 (4-granule XOR swizzle). 2-phase dbuf, 48 KB LDS.
// ---------------------------------------------------------------------------
__global__ __launch_bounds__(256) void k_init(
    const float* __restrict__ x, const unsigned short* __restrict__ Wt,
    const float* __restrict__ bW, float* __restrict__ hout,
    unsigned short* __restrict__ hb, f16* __restrict__ cb)
{
  __shared__ __attribute__((aligned(16))) float          As[2][BM * BK];   // 2x16 KB
  __shared__ __attribute__((aligned(16))) unsigned short Bs[2][BM * BK];   // 2x 8 KB
  const int t = threadIdx.x;
  const int lane = t & 63, w = t >> 6;
  const int wm = w >> 1, wn = w & 1;
  const int lr = lane & 15, ls = lane >> 4;

  const int nwg = gridDim.x;
  const int wg = (blockIdx.x & 7) * (nwg >> 3) + (blockIdx.x >> 3);
  const int mblk = wg >> 2, nblk = wg & 3;
  const int tileM = mblk * BM, tileN = nblk * 128;

  f32x4 acc[4][4];
  #pragma unroll
  for (int i = 0; i < 4; ++i)
    #pragma unroll
    for (int j = 0; j < 4; ++j)
      #pragma unroll
      for (int e = 0; e < 4; ++e) acc[i][j][e] = 0.f;

  const int arow  = lane >> 3;                       // A: 8 rows / 1KB issue (f32)
  const int aglog = (lane & 7) ^ arow;               // src granule = g ^ (row&7)
  const int brow  = lane >> 2;                       // B: 16 rows / 1KB issue (bf16)
  const int bswz  = ((lane & 3) ^ ((lane >> 3) & 3)) * 8;

  auto stage = [&](int k0, int buf) {
    #pragma unroll
    for (int s = 0; s < 4; ++s) {
      int e = w * 4 + s;
      int col = k0 + aglog * 4;
      if (col >= XSZ) col = 0;                 // pad lanes: finite garbage * B(0) = 0
      const float* g = x + (size_t)(LEAF0 + tileM + e * 8 + arow) * XSZ + col;
      gld_lds16(g, (char*)As[buf] + e * 1024);
    }
    #pragma unroll
    for (int s = 0; s < 2; ++s) {
      int e = w * 2 + s;
      const unsigned short* g = Wt + (size_t)(tileN + e * 16 + brow) * KX + k0 + bswz;
      gld_lds16(g, (char*)Bs[buf] + e * 1024);
    }
  };

  const int NT = KX / BK;                      // 10
  stage(0, 0);
  for (int it = 0; it < NT; ++it) {
    __syncthreads();
    if (it + 1 < NT) stage((it + 1) * BK, (it + 1) & 1);
    const int cur = it & 1;
    bf16x8 af[4], bfv[4];
    #pragma unroll
    for (int i = 0; i < 4; ++i) {
      int row = wm * 64 + i * 16 + lr;
      int gx = (2 * ls) ^ (lr & 7);
      f32x4 a0 = *(const f32x4*)((const char*)As[cur] + row * 128 + (gx << 4));
      f32x4 a1 = *(const f32x4*)((const char*)As[cur] + row * 128 + ((gx ^ 1) << 4));
      af[i] = pack8(a0, a1);
    }
    #pragma unroll
    for (int j = 0; j < 4; ++j) {
      int row = wn * 64 + j * 16 + lr;
      bfv[j] = *(const bf16x8*)((const char*)Bs[cur] + row * 64 + ((ls ^ ((lr >> 1) & 3)) << 4));
    }
    #pragma unroll
    for (int i = 0; i < 4; ++i)
      #pragma unroll
      for (int j = 0; j < 4; ++j)
        acc[i][j] = __builtin_amdgcn_mfma_f32_16x16x32_bf16(af[i], bfv[j], acc[i][j], 0, 0, 0);
  }

  const int pc = tileN + wn * 64;
  #pragma unroll
  for (int i = 0; i < 4; ++i) {
    #pragma unroll
    for (int tt = 0; tt < 2; ++tt) {
      int col = (pc >> 1) + tt * 16 + lr;
      #pragma unroll
      for (int rr = 0; rr < 4; ++rr) {
        int row = tileM + wm * 64 + i * 16 + ls * 4 + rr;
        float th = ftanh_(acc[i][2 * tt][rr]     + bW[col]);
        float tc = ftanh_(acc[i][2 * tt + 1][rr] + bW[256 + col]);
        size_t node = (size_t)LEAF0 + row;
        hout[node * HSZ + col] = th;
        hb[node * HSZ + col]   = f2bf(th);
        cb[node * HSZ + col]   = (f16)tc;
      }
    }
  }
}

// ---------------------------------------------------------------------------
// One tree level (d >= 12), fused, all-bf16 staging, 2-phase dbuf (R6-proven).
// ---------------------------------------------------------------------------
__global__ __launch_bounds__(256) void k_level(
    float* __restrict__ hbuf, unsigned short* __restrict__ hb,
    f16* __restrict__ cb,
    const unsigned short* __restrict__ Ut, const float* __restrict__ bU,
    int a, int m)
{
  __shared__ __attribute__((aligned(16))) unsigned short As[2][BM * BK];   // 2x8 KB
  __shared__ __attribute__((aligned(16))) unsigned short Bs[2][BM * BK];   // 2x8 KB
  const int t = threadIdx.x;
  const int lane = t & 63, w = t >> 6;
  const int wm = w >> 1, wn = w & 1;
  const int lr = lane & 15, ls = lane >> 4;

  const int nwg = gridDim.x;
  const int wg = (blockIdx.x & 7) * (nwg >> 3) + (blockIdx.x >> 3);
  const int mblk = wg >> 3, nblk = wg & 7;
  const int tileM = mblk * BM, tileN = nblk * 128;

  f32x4 acc[4][4];
  #pragma unroll
  for (int i = 0; i < 4; ++i)
    #pragma unroll
    for (int j = 0; j < 4; ++j)
      #pragma unroll
      for (int e = 0; e < 4; ++e) acc[i][j][e] = 0.f;

  const unsigned short* Abase = hb + (size_t)(2 * a + 1) * HSZ + (size_t)tileM * KU;
  const unsigned short* Bbase = Ut + (size_t)tileN * KU;

  const int brow = lane >> 2;
  const int bswz = ((lane & 3) ^ ((lane >> 3) & 3)) * 8;

  auto stage = [&](int k0, int buf) {
    #pragma unroll
    for (int s = 0; s < 2; ++s) {
      int e = w * 2 + s;
      const unsigned short* g = Abase + (size_t)(e * 16 + brow) * KU + k0 + bswz;
      gld_lds16(g, (char*)As[buf] + e * 1024);
    }
    #pragma unroll
    for (int s = 0; s < 2; ++s) {
      int e = w * 2 + s;
      const unsigned short* g = Bbase + (size_t)(e * 16 + brow) * KU + k0 + bswz;
      gld_lds16(g, (char*)Bs[buf] + e * 1024);
    }
  };

  const int NT = KU / BK;                      // 16
  stage(0, 0);
  for (int it = 0; it < NT; ++it) {
    __syncthreads();
    if (it + 1 < NT) stage((it + 1) * BK, (it + 1) & 1);
    const int cur = it & 1;
    bf16x8 af[4], bfv[4];
    #pragma unroll
    for (int i = 0; i < 4; ++i) {
      int row = wm * 64 + i * 16 + lr;
      af[i] = *(const bf16x8*)((const char*)As[cur] + row * 64 + ((ls ^ ((lr >> 1) & 3)) << 4));
    }
    #pragma unroll
    for (int j = 0; j < 4; ++j) {
      int row = wn * 64 + j * 16 + lr;
      bfv[j] = *(const bf16x8*)((const char*)Bs[cur] + row * 64 + ((ls ^ ((lr >> 1) & 3)) << 4));
    }
    #pragma unroll
    for (int i = 0; i < 4; ++i)
      #pragma unroll
      for (int j = 0; j < 4; ++j)
        acc[i][j] = __builtin_amdgcn_mfma_f32_16x16x32_bf16(af[i], bfv[j], acc[i][j], 0, 0, 0);
  }

  const int pc = tileN + wn * 64;            // frag j == gate g
  const int col = (pc >> 2) + lr;
  const float bi = bU[col], bo = bU[256 + col], bu = bU[512 + col], bff = bU[768 + col];
  #pragma unroll
  for (int i = 0; i < 4; ++i) {
    #pragma unroll
    for (int rr = 0; rr < 4; ++rr) {
      int noderow = tileM + wm * 64 + i * 16 + ls * 4 + rr;
      if (noderow < m) {
        float iv = fsig  (acc[i][0][rr] + bi);
        float ov = fsig  (acc[i][1][rr] + bo);
        float uv = ftanh_(acc[i][2][rr] + bu);
        float fv = fsig  (acc[i][3][rr] + bff);
        size_t node = (size_t)a + noderow;
        float cl = (float)cb[(2 * node + 1) * HSZ + col];
        float cr = (float)cb[(2 * node + 2) * HSZ + col];
        float cn = iv * uv + fv * (cl + cr);
        float hn = ov * ftanh_(cn);
        hbuf[node * HSZ + col] = hn;
        hb[node * HSZ + col]   = f2bf(hn);
        cb[node * HSZ + col]   = (f16)cn;
      }
    }
  }
}

// ---------------------------------------------------------------------------
// Small levels (d <= 11): one wave per 16x64 output tile, direct global reads
// (A slab and Ut are L2-resident at these sizes). grid = max(1,m/64)*16.
// ---------------------------------------------------------------------------
__global__ __launch_bounds__(256) void k_small(
    float* __restrict__ hbuf, unsigned short* __restrict__ hb,
    f16* __restrict__ cb,
    const unsigned short* __restrict__ Ut, const float* __restrict__ bU,
    int a, int m)
{
  const int t = threadIdx.x;
  const int lane = t & 63, w = t >> 6;
  const int lr = lane & 15, ls = lane >> 4;
  const int rb = (blockIdx.x >> 4) * 64 + w * 16;
  const int nb = (blockIdx.x & 15) * 64;
  if (rb >= m) return;

  const unsigned short* Arow = hb + (size_t)(2 * a + 1) * HSZ + (size_t)(rb + lr) * KU;
  const unsigned short* B0 = Ut + (size_t)(nb + lr) * KU;

  f32x4 acc[4];
  #pragma unroll
  for (int g = 0; g < 4; ++g)
    #pragma unroll
    for (int e = 0; e < 4; ++e) acc[g][e] = 0.f;

  for (int k0 = 0; k0 < KU; k0 += BK) {
    bf16x8 av = *(const bf16x8*)(Arow + k0 + ls * 8);
    #pragma unroll
    for (int g = 0; g < 4; ++g) {
      bf16x8 bv = *(const bf16x8*)(B0 + (size_t)g * 16 * KU + k0 + ls * 8);
      acc[g] = __builtin_amdgcn_mfma_f32_16x16x32_bf16(av, bv, acc[g], 0, 0, 0);
    }
  }

  const int col = (nb >> 2) + lr;
  const float bi = bU[col], bo = bU[256 + col], bu = bU[512 + col], bff = bU[768 + col];
  #pragma unroll
  for (int rr = 0; rr < 4; ++rr) {
    int row = rb + ls * 4 + rr;
    if (row < m) {
      float iv = fsig  (acc[0][rr] + bi);
      float ov = fsig  (acc[1][rr] + bo);
      float uv = ftanh_(acc[2][rr] + bu);
      float fv = fsig  (acc[3][rr] + bff);
      size_t node = (size_t)a + row;
      float cl = (float)cb[(2 * node + 1) * HSZ + col];
      float cr = (float)cb[(2 * node + 2) * HSZ + col];
      float cn = iv * uv + fv * (cl + cr);
      float hn = ov * ftanh_(cn);
      hbuf[node * HSZ + col] = hn;
      hb[node * HSZ + col]   = f2bf(hn);
      cb[node * HSZ + col]   = (f16)cn;
    }
  }
}

// ---------------------------------------------------------------------------
extern "C" void kernel_launch(void* const* d_in, const int* in_sizes, int n_in,
                              void* d_out, int out_size, void* d_ws, size_t ws_size,
                              hipStream_t stream) {
  const float* x  = (const float*)d_in[0];
  const float* W  = (const float*)d_in[1];
  const float* bW = (const float*)d_in[2];
  const float* U  = (const float*)d_in[3];
  const float* bU = (const float*)d_in[4];
  // d_in[5] = children (int32) — structurally 2i+1/2i+2 (complete binary tree).
  float* hout = (float*)d_out;
  char*  ws   = (char*)d_ws;

  // ws layout (269,810,688 B total):
  unsigned short* Ut = (unsigned short*)ws;                         // 1,048,576
  unsigned short* Wt = (unsigned short*)(ws + 1048576);             //   327,680
  f16*            cb = (f16*)(ws + 1048576 + 327680);               // 134,217,216
  unsigned short* hb = (unsigned short*)(ws + 1048576 + 327680
                                         + (size_t)N_NODES * HSZ * 2); // 134,217,216

  const int preptot = GATES * KU + WCOLS * KX;
  hipLaunchKernelGGL(k_prep, dim3((preptot + 255) / 256), dim3(256), 0, stream, W, U, Wt, Ut);

  hipLaunchKernelGGL(k_init, dim3((N_LEAF / BM) * 4), dim3(256), 0, stream,
                     x, Wt, bW, hout, hb, cb);

  for (int d = 16; d >= 0; --d) {
    int m = 1 << d, a = m - 1;
    if (d >= 12) {
      hipLaunchKernelGGL(k_level, dim3((m / BM) * 8), dim3(256), 0, stream,
                         hout, hb, cb, Ut, bU, a, m);
    } else {
      int gm = (m + 63) / 64; if (gm < 1) gm = 1;
      hipLaunchKernelGGL(k_small, dim3(gm * 16), dim3(256), 0, stream,
                         hout, hb, cb, Ut, bU, a, m);
    }
  }
}